// Round 4
// baseline (215.727 us; speedup 1.0000x reference)
//
#include <hip/hip_runtime.h>
#include <hip/hip_bf16.h>
#include <math.h>

#define NB 4096
#define NC 8192
#define ND 128
#define NSPLIT 16
#define CPS (NC / NSPLIT)          // 512 centers per split
#define NTILES (CPS / 16)          // 32 center-tiles per split

// ws layout (float offsets). [0]=loss_sum [1]=tril_sum [2]=pull_sum [3]=ticket
#define WS_XN 16
#define WS_CN (WS_XN + NB)                    // 4112
#define WS_POS (WS_CN + NC)                   // 12304
#define WS_PART (WS_POS + NB)                 // 16400, size NB*NSPLIT*10
#define WS_XB (WS_PART + NB * NSPLIT * 10)    // 671760, bf16 x as ushort[NB*ND]
#define WS_CB (WS_XB + NB * ND / 2)           // 933904, bf16 centers as ushort[NC*ND]

typedef __attribute__((ext_vector_type(8))) short short8v;   // 8 x bf16 frag
typedef __attribute__((ext_vector_type(4))) float f32x4;

// one wave per row: norm (f32) + bf16 conversion; block 0 zeroes accumulators
__global__ __launch_bounds__(256) void prep_kernel(
    const float* __restrict__ x, const float* __restrict__ c, float* __restrict__ ws) {
  if (blockIdx.x == 0 && threadIdx.x < 16) ws[threadIdx.x] = 0.0f;
  int wid = threadIdx.x >> 6, lane = threadIdx.x & 63;
  int row = blockIdx.x * 4 + wid;
  const float* src;
  float* ndst;
  ushort* bdst;
  if (row < NB) {
    src = x + (size_t)row * ND;
    ndst = ws + WS_XN + row;
    bdst = (ushort*)(ws + WS_XB) + (size_t)row * ND;
  } else {
    int r = row - NB;
    src = c + (size_t)r * ND;
    ndst = ws + WS_CN + r;
    bdst = (ushort*)(ws + WS_CB) + (size_t)r * ND;
  }
  float2 v = *(const float2*)(src + lane * 2);
  __hip_bfloat16 h0 = __float2bfloat16(v.x);
  __hip_bfloat16 h1 = __float2bfloat16(v.y);
  ushort2 u;
  u.x = *(ushort*)&h0;
  u.y = *(ushort*)&h1;
  *(ushort2*)(bdst + lane * 2) = u;
  float s = fmaf(v.x, v.x, v.y * v.y);
#pragma unroll
  for (int off = 32; off; off >>= 1) s += __shfl_down(s, off, 64);
  if (lane == 0) *ndst = s;
}

#define INS10(arr, val)                          \
  {                                              \
    float _v = (val);                            \
    _Pragma("unroll") for (int _k = 0; _k < 10; ++_k) { \
      float _mx = fmaxf(arr[_k], _v);            \
      _v = fminf(arr[_k], _v);                   \
      arr[_k] = _mx;                             \
    }                                            \
  }

// fused x@centers^T (bf16 MFMA, swapped operands) + lane-local top-10 + pos capture
__global__ __launch_bounds__(256) void xloss_kernel(
    const int* __restrict__ labels, float* __restrict__ ws) {
  int t = threadIdx.x;
  int w = t >> 6, l = t & 63, lo = l & 15, hi = l >> 4;
  int row = blockIdx.x * 64 + w * 16 + lo;
  int split = blockIdx.y;
  int cbase = split * CPS;

  const ushort* xb = (const ushort*)(ws + WS_XB);
  const ushort* cb = (const ushort*)(ws + WS_CB);

  const ushort* xrp = xb + (size_t)row * ND + hi * 8;
  short8v xf0 = *(const short8v*)(xrp + 0);
  short8v xf1 = *(const short8v*)(xrp + 32);
  short8v xf2 = *(const short8v*)(xrp + 64);
  short8v xf3 = *(const short8v*)(xrp + 96);

  float xn = ws[WS_XN + row];
  int lab = labels[row];

  float top[10];
#pragma unroll
  for (int k = 0; k < 10; ++k) top[k] = -3.0e38f;
  float posv = -3.0e38f;

  for (int tl = 0; tl < NTILES; ++tl) {
    int c0 = cbase + tl * 16;
    const ushort* cp = cb + (size_t)(c0 + lo) * ND + hi * 8;
    short8v a0 = *(const short8v*)(cp + 0);
    short8v a1 = *(const short8v*)(cp + 32);
    short8v a2 = *(const short8v*)(cp + 64);
    short8v a3 = *(const short8v*)(cp + 96);
    f32x4 acc = {0.f, 0.f, 0.f, 0.f};
    acc = __builtin_amdgcn_mfma_f32_16x16x32_bf16(a0, xf0, acc, 0, 0, 0);
    acc = __builtin_amdgcn_mfma_f32_16x16x32_bf16(a1, xf1, acc, 0, 0, 0);
    acc = __builtin_amdgcn_mfma_f32_16x16x32_bf16(a2, xf2, acc, 0, 0, 0);
    acc = __builtin_amdgcn_mfma_f32_16x16x32_bf16(a3, xf3, acc, 0, 0, 0);

    f32x4 cn4 = *(const f32x4*)(ws + WS_CN + c0 + hi * 4);
#pragma unroll
    for (int r = 0; r < 4; ++r) {
      int cidx = c0 + hi * 4 + r;
      float dist = xn + cn4[r] - 2.0f * acc[r];
      dist = fminf(fmaxf(dist, 1e-12f), 1e12f);
      float s = -dist;
      bool isl = (cidx == lab);
      posv = isl ? s : posv;
      float se = isl ? -3.0e38f : s;
      INS10(top, se)
    }
  }

  float oth[10];
#pragma unroll
  for (int m = 16; m <= 32; m <<= 1) {
#pragma unroll
    for (int k = 0; k < 10; ++k) oth[k] = __shfl_xor(top[k], m, 64);
#pragma unroll
    for (int k = 0; k < 10; ++k) INS10(top, oth[k])
  }

  if (posv > -1.0e37f) ws[WS_POS + row] = posv;
  if (hi == 0) {
    float* dst = ws + WS_PART + ((size_t)row * NSPLIT + split) * 10;
#pragma unroll
    for (int k = 0; k < 10; ++k) dst[k] = top[k];
  }
}

// centers x centers^T; 128x64 tile per block; LDS-staged fill-style coalesced stores
__global__ __launch_bounds__(256) void c2c_kernel(
    float* __restrict__ ws, float* __restrict__ outmat) {
  __shared__ float tile[128][65];
  __shared__ float red[4];
  int bi = blockIdx.x;                  // 64  row-chunks of 128
  int bj = blockIdx.y;                  // 128 col-chunks of 64
  int t = threadIdx.x;
  int w = t >> 6, l = t & 63, lo = l & 15, hi = l >> 4;
  int wm = w >> 1, wn = w & 1;
  int rowb = bi * 128 + wm * 64;        // wave: 64 rows (4 m-tiles)
  int colb = bj * 64 + wn * 32;         // wave: 32 cols (2 n-tiles)
  const ushort* cb = (const ushort*)(ws + WS_CB);

  f32x4 acc[4][2];
#pragma unroll
  for (int m = 0; m < 4; ++m)
#pragma unroll
    for (int n = 0; n < 2; ++n) acc[m][n] = (f32x4){0.f, 0.f, 0.f, 0.f};

#pragma unroll
  for (int ks = 0; ks < 4; ++ks) {
    short8v af[4], bf[2];
#pragma unroll
    for (int m = 0; m < 4; ++m)
      af[m] = *(const short8v*)(cb + (size_t)(rowb + m * 16 + lo) * ND + ks * 32 + hi * 8);
#pragma unroll
    for (int n = 0; n < 2; ++n)
      bf[n] = *(const short8v*)(cb + (size_t)(colb + n * 16 + lo) * ND + ks * 32 + hi * 8);
#pragma unroll
    for (int m = 0; m < 4; ++m)
#pragma unroll
      for (int n = 0; n < 2; ++n)
        acc[m][n] = __builtin_amdgcn_mfma_f32_16x16x32_bf16(af[m], bf[n], acc[m][n], 0, 0, 0);
  }

  float cnj[2];
#pragma unroll
  for (int n = 0; n < 2; ++n) cnj[n] = ws[WS_CN + colb + n * 16 + lo];
  float tsum = 0.0f;
#pragma unroll
  for (int m = 0; m < 4; ++m) {
    f32x4 cni = *(const f32x4*)(ws + WS_CN + rowb + m * 16 + hi * 4);
#pragma unroll
    for (int n = 0; n < 2; ++n) {
#pragma unroll
      for (int rr = 0; rr < 4; ++rr) {
        int lr = wm * 64 + m * 16 + hi * 4 + rr;     // local row 0..127
        int lc = wn * 32 + n * 16 + lo;              // local col 0..63
        int gr = bi * 128 + lr;
        int gc = bj * 64 + lc;
        float dd = cni[rr] + cnj[n] - 2.0f * acc[m][n][rr];
        dd = fminf(fmaxf(dd, 1e-12f), 1e12f);
        tsum += (gr > gc) ? dd : 0.0f;
        tile[lr][lc] = dd;
      }
    }
  }

#pragma unroll
  for (int off = 32; off; off >>= 1) tsum += __shfl_down(tsum, off, 64);
  if (l == 0) red[w] = tsum;
  __syncthreads();                       // staging + reduction barrier
  if (t == 0) atomicAdd(ws + 1, red[0] + red[1] + red[2] + red[3]);

  // fill-style stores: each wave-inst writes 4 complete 256B rows
  int tr0 = t >> 4, c4 = (t & 15) << 2;
  float* ob = outmat + (size_t)(bi * 128) * NC + bj * 64 + c4;
#pragma unroll
  for (int p = 0; p < 8; ++p) {
    int tr = p * 16 + tr0;
    *(f32x4*)(ob + (size_t)tr * NC) = *(const f32x4*)&tile[tr][c4];
  }
}

// per-row 16-way merge + LSE; last block (device ticket) finalizes scalars
__global__ __launch_bounds__(256) void merge_fin_kernel(float* __restrict__ ws,
                                                        float* __restrict__ out) {
  int row = blockIdx.x * 256 + threadIdx.x;
  const f32x4* part = (const f32x4*)(ws + WS_PART + (size_t)row * NSPLIT * 10);
  float top[10];
#pragma unroll
  for (int k = 0; k < 10; ++k) top[k] = -3.0e38f;
#pragma unroll
  for (int i = 0; i < NSPLIT * 10 / 4; ++i) {
    f32x4 v = part[i];
    INS10(top, v.x)
    INS10(top, v.y)
    INS10(top, v.z)
    INS10(top, v.w)
  }
  float pos = ws[WS_POS + row];
  float mx = fmaxf(pos, top[0]);
  float ssum = expf(pos - mx);
#pragma unroll
  for (int k = 0; k < 10; ++k) ssum += expf(top[k] - mx);
  float lrow = mx + logf(ssum) - pos;
  float prow = -pos;
#pragma unroll
  for (int off = 32; off; off >>= 1) {
    lrow += __shfl_down(lrow, off, 64);
    prow += __shfl_down(prow, off, 64);
  }
  if ((threadIdx.x & 63) == 0) {
    atomicAdd(ws + 0, lrow);
    atomicAdd(ws + 2, prow);
  }
  __syncthreads();
  if (threadIdx.x == 0) {
    __threadfence();
    unsigned tk = atomicAdd((unsigned int*)(ws + 3), 1u);
    if (tk == 15u) {
      float ls = atomicAdd(ws + 0, 0.0f);
      float ts = atomicAdd(ws + 1, 0.0f);
      float ps = atomicAdd(ws + 2, 0.0f);
      out[0] = ls / 4096.0f;
      out[1] = -ts / 33550336.0f;          // C*(C-1)/2
      out[2 + (size_t)NC * NC] = ps / 4096.0f;
    }
  }
}

extern "C" void kernel_launch(void* const* d_in, const int* in_sizes, int n_in,
                              void* d_out, int out_size, void* d_ws, size_t ws_size,
                              hipStream_t stream) {
  const float* x = (const float*)d_in[0];
  const int* labels = (const int*)d_in[1];
  const float* centers = (const float*)d_in[2];
  float* out = (float*)d_out;
  float* ws = (float*)d_ws;

  hipLaunchKernelGGL(prep_kernel, dim3((NB + NC) / 4), dim3(256), 0, stream, x, centers, ws);
  hipLaunchKernelGGL(xloss_kernel, dim3(64, NSPLIT), dim3(256), 0, stream, labels, ws);
  hipLaunchKernelGGL(c2c_kernel, dim3(64, 128), dim3(256), 0, stream, ws, out + 2);
  hipLaunchKernelGGL(merge_fin_kernel, dim3(NB / 256), dim3(256), 0, stream, ws, out);
}